// Round 1
// baseline (438.633 us; speedup 1.0000x reference)
//
#include <hip/hip_runtime.h>

#define N_PTS 131072
#define C_DIM 128
#define NS_K  16
#define BN_EPS 1e-5f

// ---------------------------------------------------------------------------
// GEMM: out[N,128] = A[N,128] @ W[128,128] + bias ; optional BN stats
// Block tile: 128 rows x 128 cols, BK=32. 256 threads, 8x8 micro-tile each.
// Thread (ty=tid>>4, tx=tid&15): rows ty+16*i (i<8), cols {tx*4+j, tx*4+64+j}.
// ---------------------------------------------------------------------------
template <bool STATS>
__global__ __launch_bounds__(256) void gemm128_kernel(
    const float* __restrict__ A, const float* __restrict__ W,
    const float* __restrict__ bias, float* __restrict__ out,
    float* __restrict__ gsum, float* __restrict__ gsq)
{
    __shared__ float a_s[128 * 36];   // padded stride 36: bank-spread + 16B aligned
    __shared__ float w_s[32 * 128];
    __shared__ float s_sum[128];
    __shared__ float s_sq[128];

    const int tid = threadIdx.x;
    const int tx = tid & 15;
    const int ty = tid >> 4;
    const long long base = (long long)blockIdx.x * 128;

    float acc[8][8];
    #pragma unroll
    for (int i = 0; i < 8; i++)
        #pragma unroll
        for (int j = 0; j < 8; j++) acc[i][j] = 0.f;

    if (STATS && tid < 128) { s_sum[tid] = 0.f; s_sq[tid] = 0.f; }

    const int row_l = tid >> 1;        // 0..127
    const int half  = (tid & 1) * 16;  // 0 or 16

    for (int k0 = 0; k0 < 128; k0 += 32) {
        __syncthreads();
        // stage A tile: 128 rows x 32 cols
        {
            const float* ag = A + (base + row_l) * 128 + k0 + half;
            float* as = a_s + row_l * 36 + half;
            #pragma unroll
            for (int j = 0; j < 4; j++)
                *(float4*)(as + 4 * j) = *(const float4*)(ag + 4 * j);
        }
        // stage W tile: 32 rows x 128 cols
        {
            const int kk = tid >> 3;
            const int cb = (tid & 7) * 16;
            const float* wg = W + (long long)(k0 + kk) * 128 + cb;
            float* ws = w_s + kk * 128 + cb;
            #pragma unroll
            for (int j = 0; j < 4; j++)
                *(float4*)(ws + 4 * j) = *(const float4*)(wg + 4 * j);
        }
        __syncthreads();

        #pragma unroll
        for (int kk = 0; kk < 32; kk++) {
            const float4 w0 = *(const float4*)(w_s + kk * 128 + tx * 4);
            const float4 w1 = *(const float4*)(w_s + kk * 128 + tx * 4 + 64);
            #pragma unroll
            for (int i = 0; i < 8; i++) {
                const float a = a_s[(ty + 16 * i) * 36 + kk];
                acc[i][0] = fmaf(a, w0.x, acc[i][0]);
                acc[i][1] = fmaf(a, w0.y, acc[i][1]);
                acc[i][2] = fmaf(a, w0.z, acc[i][2]);
                acc[i][3] = fmaf(a, w0.w, acc[i][3]);
                acc[i][4] = fmaf(a, w1.x, acc[i][4]);
                acc[i][5] = fmaf(a, w1.y, acc[i][5]);
                acc[i][6] = fmaf(a, w1.z, acc[i][6]);
                acc[i][7] = fmaf(a, w1.w, acc[i][7]);
            }
        }
    }

    const int c0 = tx * 4;
    const int c1 = tx * 4 + 64;
    const float4 b0 = *(const float4*)(bias + c0);
    const float4 b1 = *(const float4*)(bias + c1);

    float psum[8], psq[8];
    #pragma unroll
    for (int j = 0; j < 8; j++) { psum[j] = 0.f; psq[j] = 0.f; }

    #pragma unroll
    for (int i = 0; i < 8; i++) {
        const long long r = base + ty + 16 * i;
        float4 v0, v1;
        v0.x = acc[i][0] + b0.x; v0.y = acc[i][1] + b0.y;
        v0.z = acc[i][2] + b0.z; v0.w = acc[i][3] + b0.w;
        v1.x = acc[i][4] + b1.x; v1.y = acc[i][5] + b1.y;
        v1.z = acc[i][6] + b1.z; v1.w = acc[i][7] + b1.w;
        *(float4*)(out + r * 128 + c0) = v0;
        *(float4*)(out + r * 128 + c1) = v1;
        if (STATS) {
            psum[0] += v0.x; psq[0] += v0.x * v0.x;
            psum[1] += v0.y; psq[1] += v0.y * v0.y;
            psum[2] += v0.z; psq[2] += v0.z * v0.z;
            psum[3] += v0.w; psq[3] += v0.w * v0.w;
            psum[4] += v1.x; psq[4] += v1.x * v1.x;
            psum[5] += v1.y; psq[5] += v1.y * v1.y;
            psum[6] += v1.z; psq[6] += v1.z * v1.z;
            psum[7] += v1.w; psq[7] += v1.w * v1.w;
        }
    }

    if (STATS) {
        #pragma unroll
        for (int j = 0; j < 4; j++) {
            atomicAdd(&s_sum[c0 + j], psum[j]);
            atomicAdd(&s_sq[c0 + j],  psq[j]);
            atomicAdd(&s_sum[c1 + j], psum[4 + j]);
            atomicAdd(&s_sq[c1 + j],  psq[4 + j]);
        }
        __syncthreads();
        if (tid < 128) {
            atomicAdd(&gsum[tid], s_sum[tid]);
            atomicAdd(&gsq[tid],  s_sq[tid]);
        }
    }
}

// ---------------------------------------------------------------------------
// Laplacian: lap[i,c] = mean_s relu(u_pre[idx[i,s],c] - u_pre[i,c])
// 2 points per 256-thread block (one per pair of waves); c = tid&127.
// ---------------------------------------------------------------------------
__global__ __launch_bounds__(256) void laplacian_kernel(
    const float* __restrict__ upre, const int* __restrict__ idx,
    float* __restrict__ lap)
{
    const int tid = threadIdx.x;
    const long long pt = (long long)blockIdx.x * 2 + (tid >> 7);
    const int c = tid & 127;

    const float center = upre[pt * 128 + c];
    const int* ip = idx + pt * NS_K;
    float acc = 0.f;
    #pragma unroll
    for (int s = 0; s < NS_K; s++) {
        const long long j = ip[s];
        const float v = upre[j * 128 + c] - center;
        acc += fmaxf(v, 0.f);
    }
    lap[pt * 128 + c] = acc * (1.f / (float)NS_K);
}

// ---------------------------------------------------------------------------
// BN (training stats) + ReLU: one float4 of h per thread.
// ---------------------------------------------------------------------------
__global__ __launch_bounds__(256) void bn_relu_kernel(
    const float* __restrict__ h, const float* __restrict__ gsum,
    const float* __restrict__ gsq, const float* __restrict__ gamma,
    const float* __restrict__ beta, float* __restrict__ out)
{
    const long long i = (long long)blockIdx.x * 256 + threadIdx.x;  // float4 idx
    const int c0 = (int)((i * 4) & 127);
    const float4 hv = *(const float4*)(h + i * 4);
    const float invN = 1.f / (float)N_PTS;

    float r[4];
    const float he[4] = { hv.x, hv.y, hv.z, hv.w };
    #pragma unroll
    for (int e = 0; e < 4; e++) {
        const int c = c0 + e;
        const float mean = gsum[c] * invN;
        const float var  = gsq[c] * invN - mean * mean;
        const float sc   = rsqrtf(var + BN_EPS) * gamma[c];
        const float o    = fmaf(he[e] - mean, sc, beta[c]);
        r[e] = fmaxf(o, 0.f);
    }
    float4 ov; ov.x = r[0]; ov.y = r[1]; ov.z = r[2]; ov.w = r[3];
    *(float4*)(out + (long long)3 * N_PTS + i * 4) = ov;
}

// ---------------------------------------------------------------------------
// Copy p (N*3 floats) and write o (as float, matching f32 out buffer read).
// ---------------------------------------------------------------------------
__global__ __launch_bounds__(256) void copy_p_kernel(
    const float* __restrict__ p, const int* __restrict__ o,
    float* __restrict__ out)
{
    const long long i = (long long)blockIdx.x * 256 + threadIdx.x;  // float4 idx
    *(float4*)(out + i * 4) = *(const float4*)(p + i * 4);
    if (i == 0)
        out[(long long)3 * N_PTS + (long long)N_PTS * C_DIM] = (float)o[0];
}

extern "C" void kernel_launch(void* const* d_in, const int* in_sizes, int n_in,
                              void* d_out, int out_size, void* d_ws, size_t ws_size,
                              hipStream_t stream) {
    const float* p     = (const float*)d_in[0];
    const float* u     = (const float*)d_in[1];
    const int*   o     = (const int*)d_in[2];
    const int*   idx   = (const int*)d_in[3];
    const float* W1    = (const float*)d_in[4];
    const float* b1    = (const float*)d_in[5];
    const float* W2    = (const float*)d_in[6];
    const float* b2    = (const float*)d_in[7];
    const float* gamma = (const float*)d_in[8];
    const float* beta  = (const float*)d_in[9];
    float* out = (float*)d_out;

    char* ws = (char*)d_ws;
    const size_t buf_bytes = (size_t)N_PTS * C_DIM * sizeof(float);  // 64 MB
    float* upre  = (float*)ws;                        // reused as h after laplacian
    float* lap   = (float*)(ws + buf_bytes);
    float* stats = (float*)(ws + 2 * buf_bytes);      // [0:128)=sum, [128:256)=sumsq

    hipMemsetAsync(stats, 0, 256 * sizeof(float), stream);

    // u_pre = u @ W1 + b1
    gemm128_kernel<false><<<N_PTS / 128, 256, 0, stream>>>(
        u, W1, b1, upre, nullptr, nullptr);
    // lap = mean_s relu(u_pre[idx] - u_pre)
    laplacian_kernel<<<N_PTS / 2, 256, 0, stream>>>(upre, idx, lap);
    // h = lap @ W2 + b2 (+ BN partial sums); h overwrites upre
    gemm128_kernel<true><<<N_PTS / 128, 256, 0, stream>>>(
        lap, W2, b2, upre, stats, stats + 128);
    // out[3N : 3N+N*C) = relu(BN(h))
    bn_relu_kernel<<<(N_PTS * C_DIM / 4) / 256, 256, 0, stream>>>(
        upre, stats, stats + 128, gamma, beta, out);
    // out[0:3N) = p ; out[last] = o
    copy_p_kernel<<<(3 * N_PTS / 4) / 256, 256, 0, stream>>>(p, o, out);
}

// Round 2
// 297.693 us; speedup vs baseline: 1.4734x; 1.4734x over previous
//
#include <hip/hip_runtime.h>

#define N_PTS 131072
#define C_DIM 128
#define NS_K  16
#define BN_EPS 1e-5f

typedef unsigned short ushort_t;
typedef unsigned short u16x8 __attribute__((ext_vector_type(8)));
typedef __bf16 bf16x8 __attribute__((ext_vector_type(8)));
typedef float f32x4 __attribute__((ext_vector_type(4)));

__device__ __forceinline__ ushort_t f2b(float f) {
    unsigned int u = __float_as_uint(f);
    u += 0x7FFFu + ((u >> 16) & 1u);          // round-to-nearest-even
    return (ushort_t)(u >> 16);
}
__device__ __forceinline__ float b2f(ushort_t h) {
    return __uint_as_float((unsigned int)h << 16);
}

// ---------------------------------------------------------------------------
// MFMA GEMM: out_bf16[N,128] = A[N,128] @ W[128,128] + bias (+ BN sums)
// Block: 256 threads (4 waves), 128 rows x 128 cols, K=128 fully LDS-resident.
// Wave w: row-tiles {2w, 2w+1}, all 8 col-tiles; 16x16x32 bf16 MFMA.
// LDS row pitch 136 bf16 (272 B) keeps ds_read_b128 16B-aligned.
// ---------------------------------------------------------------------------
template <bool A_BF16, bool STATS>
__global__ __launch_bounds__(256) void gemm_mfma_kernel(
    const void* __restrict__ Aptr, const float* __restrict__ W,
    const float* __restrict__ bias, ushort_t* __restrict__ out,
    float* __restrict__ gsum, float* __restrict__ gsq)
{
    __shared__ __align__(16) ushort_t a_sh[128 * 136];
    __shared__ __align__(16) ushort_t w_sh[128 * 136];
    __shared__ float s_sum[128];
    __shared__ float s_sq[128];

    const int tid = threadIdx.x;
    const int base = blockIdx.x * 128;

    if (STATS && tid < 128) { s_sum[tid] = 0.f; s_sq[tid] = 0.f; }

    // ---- stage A tile: 128 rows x 128 K, converted to bf16 ----
    {
        const int row  = tid >> 1;
        const int half = (tid & 1) * 64;
        ushort_t* as = a_sh + row * 136 + half;
        if (A_BF16) {
            const ushort_t* ag = (const ushort_t*)Aptr + (size_t)(base + row) * 128 + half;
            #pragma unroll
            for (int j = 0; j < 8; j++)
                *(u16x8*)(as + j * 8) = *(const u16x8*)(ag + j * 8);
        } else {
            const float* ag = (const float*)Aptr + (size_t)(base + row) * 128 + half;
            #pragma unroll
            for (int j = 0; j < 8; j++) {
                f32x4 lo = *(const f32x4*)(ag + j * 8);
                f32x4 hi = *(const f32x4*)(ag + j * 8 + 4);
                u16x8 v;
                v[0] = f2b(lo[0]); v[1] = f2b(lo[1]); v[2] = f2b(lo[2]); v[3] = f2b(lo[3]);
                v[4] = f2b(hi[0]); v[5] = f2b(hi[1]); v[6] = f2b(hi[2]); v[7] = f2b(hi[3]);
                *(u16x8*)(as + j * 8) = v;
            }
        }
    }
    // ---- stage W transposed: w_sh[n][k] = W[k][n] (coalesced reads) ----
    {
        const int n  = tid & 127;
        const int kb = (tid >> 7) * 64;
        #pragma unroll 8
        for (int k = 0; k < 64; k++)
            w_sh[n * 136 + kb + k] = f2b(W[(kb + k) * 128 + n]);
    }
    __syncthreads();

    const int lane = tid & 63;
    const int wv   = tid >> 6;
    const int m16  = lane & 15;   // row within A-tile / col within B-tile
    const int q    = lane >> 4;   // quad -> k offset q*8

    f32x4 acc[2][8];
    #pragma unroll
    for (int i = 0; i < 2; i++)
        #pragma unroll
        for (int c = 0; c < 8; c++) acc[i][c] = (f32x4){0.f, 0.f, 0.f, 0.f};

    const ushort_t* ap0 = a_sh + ((wv * 2 + 0) * 16 + m16) * 136 + q * 8;
    const ushort_t* ap1 = a_sh + ((wv * 2 + 1) * 16 + m16) * 136 + q * 8;
    const ushort_t* wp  = w_sh + m16 * 136 + q * 8;

    #pragma unroll
    for (int k0 = 0; k0 < 128; k0 += 32) {
        bf16x8 a0 = __builtin_bit_cast(bf16x8, *(const u16x8*)(ap0 + k0));
        bf16x8 a1 = __builtin_bit_cast(bf16x8, *(const u16x8*)(ap1 + k0));
        #pragma unroll
        for (int c = 0; c < 8; c++) {
            bf16x8 b = __builtin_bit_cast(bf16x8, *(const u16x8*)(wp + c * (16 * 136) + k0));
            acc[0][c] = __builtin_amdgcn_mfma_f32_16x16x32_bf16(a0, b, acc[0][c], 0, 0, 0);
            acc[1][c] = __builtin_amdgcn_mfma_f32_16x16x32_bf16(a1, b, acc[1][c], 0, 0, 0);
        }
    }

    // ---- epilogue: bias, bf16 store, optional BN partial sums ----
    float psum[8], psq[8];
    #pragma unroll
    for (int c = 0; c < 8; c++) { psum[c] = 0.f; psq[c] = 0.f; }

    #pragma unroll
    for (int c = 0; c < 8; c++) {
        const int col = c * 16 + m16;
        const float bv = bias[col];
        #pragma unroll
        for (int i = 0; i < 2; i++) {
            const int rb = base + (wv * 2 + i) * 16 + q * 4;
            #pragma unroll
            for (int r = 0; r < 4; r++) {
                const float v = acc[i][c][r] + bv;
                out[(size_t)(rb + r) * 128 + col] = f2b(v);
                if (STATS) { psum[c] += v; psq[c] += v * v; }
            }
        }
    }

    if (STATS) {
        #pragma unroll
        for (int c = 0; c < 8; c++) {
            atomicAdd(&s_sum[c * 16 + m16], psum[c]);
            atomicAdd(&s_sq[c * 16 + m16],  psq[c]);
        }
        __syncthreads();
        if (tid < 128) {
            atomicAdd(&gsum[tid], s_sum[tid]);
            atomicAdd(&gsq[tid],  s_sq[tid]);
        }
    }
}

// ---------------------------------------------------------------------------
// Laplacian on bf16 table: lap[i,c] = mean_s relu(t[idx[i,s],c] - t[i,c])
// 16 points/block; 16 threads/point; 8 channels (16B) per thread.
// ---------------------------------------------------------------------------
__global__ __launch_bounds__(256) void laplacian_kernel(
    const ushort_t* __restrict__ table, const int* __restrict__ idx,
    ushort_t* __restrict__ lap)
{
    __shared__ int s_idx[256];
    const int tid = threadIdx.x;
    s_idx[tid] = idx[blockIdx.x * 256 + tid];
    __syncthreads();

    const int p  = tid >> 4;
    const int c8 = (tid & 15) * 8;
    const size_t pt = (size_t)blockIdx.x * 16 + p;

    const u16x8 cv = *(const u16x8*)(table + pt * 128 + c8);
    float ctr[8];
    #pragma unroll
    for (int e = 0; e < 8; e++) ctr[e] = b2f(cv[e]);

    float acc[8];
    #pragma unroll
    for (int e = 0; e < 8; e++) acc[e] = 0.f;

    #pragma unroll
    for (int s = 0; s < NS_K; s++) {
        const int j = s_idx[p * 16 + s];
        const u16x8 nv = *(const u16x8*)(table + (size_t)j * 128 + c8);
        #pragma unroll
        for (int e = 0; e < 8; e++)
            acc[e] += fmaxf(b2f(nv[e]) - ctr[e], 0.f);
    }

    u16x8 o;
    #pragma unroll
    for (int e = 0; e < 8; e++) o[e] = f2b(acc[e] * (1.f / (float)NS_K));
    *(u16x8*)(lap + pt * 128 + c8) = o;
}

// ---------------------------------------------------------------------------
// Fold BN stats into per-channel scale/shift (1 block, 128 threads).
// ---------------------------------------------------------------------------
__global__ void bn_stats_kernel(const float* __restrict__ gsum,
                                const float* __restrict__ gsq,
                                const float* __restrict__ gamma,
                                const float* __restrict__ beta,
                                float* __restrict__ bnsc, float* __restrict__ bnsh)
{
    const int c = threadIdx.x;
    const float invN = 1.f / (float)N_PTS;
    const float mean = gsum[c] * invN;
    const float var  = gsq[c] * invN - mean * mean;
    const float sc   = rsqrtf(var + BN_EPS) * gamma[c];
    bnsc[c] = sc;
    bnsh[c] = fmaf(-mean, sc, beta[c]);
}

// ---------------------------------------------------------------------------
// BN apply + ReLU: 8 elems (one bf16x8 load, two float4 stores) per thread.
// ---------------------------------------------------------------------------
__global__ __launch_bounds__(256) void bn_relu_kernel(
    const ushort_t* __restrict__ h, const float* __restrict__ bnsc,
    const float* __restrict__ bnsh, float* __restrict__ out)
{
    const size_t i = (size_t)blockIdx.x * 256 + threadIdx.x;
    const int c8 = (threadIdx.x * 8) & 127;   // block covers 2048 elems = 16 full rows

    const u16x8 hv = *(const u16x8*)(h + i * 8);
    const f32x4 sc0 = *(const f32x4*)(bnsc + c8);
    const f32x4 sc1 = *(const f32x4*)(bnsc + c8 + 4);
    const f32x4 sh0 = *(const f32x4*)(bnsh + c8);
    const f32x4 sh1 = *(const f32x4*)(bnsh + c8 + 4);

    f32x4 o0, o1;
    #pragma unroll
    for (int e = 0; e < 4; e++) {
        o0[e] = fmaxf(fmaf(b2f(hv[e]),     sc0[e], sh0[e]), 0.f);
        o1[e] = fmaxf(fmaf(b2f(hv[4 + e]), sc1[e], sh1[e]), 0.f);
    }
    float* op = out + (size_t)3 * N_PTS + i * 8;
    *(f32x4*)(op)     = o0;
    *(f32x4*)(op + 4) = o1;
}

// ---------------------------------------------------------------------------
// Copy p (N*3 floats) and write o (as float value in f32 out buffer).
// ---------------------------------------------------------------------------
__global__ __launch_bounds__(256) void copy_p_kernel(
    const float* __restrict__ p, const int* __restrict__ o,
    float* __restrict__ out)
{
    const size_t i = (size_t)blockIdx.x * 256 + threadIdx.x;
    *(f32x4*)(out + i * 4) = *(const f32x4*)(p + i * 4);
    if (i == 0)
        out[(size_t)3 * N_PTS + (size_t)N_PTS * C_DIM] = (float)o[0];
}

extern "C" void kernel_launch(void* const* d_in, const int* in_sizes, int n_in,
                              void* d_out, int out_size, void* d_ws, size_t ws_size,
                              hipStream_t stream) {
    const float* p     = (const float*)d_in[0];
    const float* u     = (const float*)d_in[1];
    const int*   o     = (const int*)d_in[2];
    const int*   idx   = (const int*)d_in[3];
    const float* W1    = (const float*)d_in[4];
    const float* b1    = (const float*)d_in[5];
    const float* W2    = (const float*)d_in[6];
    const float* b2    = (const float*)d_in[7];
    const float* gamma = (const float*)d_in[8];
    const float* beta  = (const float*)d_in[9];
    float* out = (float*)d_out;

    char* ws = (char*)d_ws;
    const size_t buf_bytes = (size_t)N_PTS * C_DIM * sizeof(ushort_t);  // 32 MB
    ushort_t* table = (ushort_t*)ws;                       // u_pre, bf16
    ushort_t* lap   = (ushort_t*)(ws + buf_bytes);         // laplacian, bf16
    ushort_t* h     = (ushort_t*)(ws + 2 * buf_bytes);     // pre-BN, bf16
    float*    stats = (float*)(ws + 3 * buf_bytes);
    float* gsum = stats;        // [128]
    float* gsq  = stats + 128;  // [128]
    float* bnsc = stats + 256;  // [128]
    float* bnsh = stats + 384;  // [128]

    hipMemsetAsync(stats, 0, 256 * sizeof(float), stream);

    gemm_mfma_kernel<false, false><<<N_PTS / 128, 256, 0, stream>>>(
        u, W1, b1, table, nullptr, nullptr);
    laplacian_kernel<<<N_PTS / 16, 256, 0, stream>>>(table, idx, lap);
    gemm_mfma_kernel<true, true><<<N_PTS / 128, 256, 0, stream>>>(
        lap, W2, b2, h, gsum, gsq);
    bn_stats_kernel<<<1, 128, 0, stream>>>(gsum, gsq, gamma, beta, bnsc, bnsh);
    bn_relu_kernel<<<(N_PTS * C_DIM / 8) / 256, 256, 0, stream>>>(
        h, bnsc, bnsh, out);
    copy_p_kernel<<<(3 * N_PTS / 4) / 256, 256, 0, stream>>>(p, o, out);
}